// Round 13
// baseline (132.348 us; speedup 1.0000x reference)
//
#include <hip/hip_runtime.h>

// Sinkhorn top-k, sorted-value domain, x <- 1/(Mx), 200 apps.
// R13 = R12 + inline-asm "+v" pin of the K band each iteration: VOP3P fdot2
// cannot source AGPRs, and R10-R12's VGPR_Count=132 (< ~150 live dwords)
// shows the allocator parks part of K2 in AGPRs -> v_accvgpr_read per use
// (~100 phantom cyc/app). The empty asm makes permanent VGPR residency the
// cheapest allocation. Arithmetic bit-identical to R12.

#define N      512
#define BATCH  16
#define KTOP   50
#define NAPPS  200
#define ND     14          // window dwords: global dwords 4l-5 .. 4l+8
#define COEF   1442.6950408889634f   // log2(e)/EPSILON, EPSILON=1e-3
#define ONEH2  0x3C003C00u

typedef _Float16 h2 __attribute__((ext_vector_type(2)));

static __device__ __forceinline__ h2 pack2(float a, float b) {
    return __builtin_bit_cast(h2, __builtin_amdgcn_cvt_pkrtz(a, b));
}
static __device__ __forceinline__ unsigned shr1(unsigned v) {   // lane i <- i-1, 0-fill
    return (unsigned)__builtin_amdgcn_update_dpp(0, (int)v, 0x138, 0xF, 0xF, true);
}
static __device__ __forceinline__ unsigned shl1(unsigned v) {   // lane i <- i+1, 0-fill
    return (unsigned)__builtin_amdgcn_update_dpp(0, (int)v, 0x130, 0xF, 0xF, true);
}
static __device__ __forceinline__ void pin_row(unsigned (&k)[ND]) {
    asm volatile("" : "+v"(k[0]), "+v"(k[1]), "+v"(k[2]), "+v"(k[3]),
                      "+v"(k[4]), "+v"(k[5]), "+v"(k[6]), "+v"(k[7]),
                      "+v"(k[8]), "+v"(k[9]), "+v"(k[10]), "+v"(k[11]),
                      "+v"(k[12]), "+v"(k[13]));
}

__global__
__attribute__((amdgpu_flat_work_group_size(64, 64), amdgpu_waves_per_eu(1, 1)))
void sinkhorn_topk_kernel(const float* __restrict__ scores,
                          float* __restrict__ out) {
    __shared__ __align__(16) float tv[N];
    __shared__ int                 ti[N];

    const int lane = threadIdx.x;           // 0..63
    const int b    = blockIdx.x;

    ((float4*)tv)[2 * lane]     = ((const float4*)(scores + b * N))[2 * lane];
    ((float4*)tv)[2 * lane + 1] = ((const float4*)(scores + b * N))[2 * lane + 1];
#pragma unroll
    for (int r = 0; r < 8; ++r) ti[8 * lane + r] = 8 * lane + r;
    __syncthreads();

    // ---- bitonic sort, descending ----
    for (int k = 2; k <= N; k <<= 1) {
        for (int j = k >> 1; j > 0; j >>= 1) {
#pragma unroll
            for (int e = 0; e < 4; ++e) {
                int q = lane + e * 64;
                int i = ((q & ~(j - 1)) << 1) | (q & (j - 1));
                int p = i | j;
                float va = tv[i], vb = tv[p];
                bool up = ((i & k) == 0);
                bool sw = up ? (va < vb) : (va > vb);
                if (sw) {
                    tv[i] = vb; tv[p] = va;
                    int t_ = ti[i]; ti[i] = ti[p]; ti[p] = t_;
                }
            }
            __syncthreads();
        }
    }

    // ---- K band: rows 8l..8l+7, col halves 8l-10..8l+17 (14 dwords) ----
    const int r0 = 8 * lane;
    const int gb = r0 - 10;
    float trow[8];
#pragma unroll
    for (int r = 0; r < 8; ++r) trow[r] = tv[r0 + r];

    unsigned K2[8][ND];                     // 112 dwords/lane
#pragma unroll
    for (int d = 0; d < ND; ++d) {
        int g0 = gb + 2 * d, g1 = g0 + 1;
        int c0 = min(max(g0, 0), N - 1), c1 = min(max(g1, 0), N - 1);
        float s0 = tv[c0], s1 = tv[c1];
#pragma unroll
        for (int r = 0; r < 8; ++r) {
            float d0 = trow[r] - s0, d1 = trow[r] - s1;
            K2[r][d] = __builtin_bit_cast(unsigned,
                         pack2(exp2f(-COEF * d0 * d0), exp2f(-COEF * d1 * d1)));
        }
    }

    // ---- x (app 0) and its window ----
    unsigned x0 = ONEH2, x1 = ONEH2, x2 = ONEH2, x3 = ONEH2;
    unsigned w[ND];
    {
        unsigned s1a = shr1(x0), s1b = shr1(x1), s1c = shr1(x2), s1d = shr1(x3);
        unsigned l1a = shl1(x0), l1b = shl1(x1), l1c = shl1(x2), l1d = shl1(x3);
        w[0] = shr1(s1d);
        w[1] = s1a;  w[2] = s1b;  w[3] = s1c;  w[4] = s1d;
        w[5] = x0;   w[6] = x1;   w[7] = x2;   w[8] = x3;
        w[9] = l1a;  w[10] = l1b; w[11] = l1c; w[12] = l1d;
        w[13] = shl1(l1a);
    }

    // ---- 199 full apps (dots + rebuild), then 1 peeled app ----
    for (int t = 0; t < NAPPS - 1; ++t) {
#pragma unroll
        for (int r = 0; r < 8; ++r) pin_row(K2[r]);   // force arch-VGPR class

        // half 1: rows 0..3
        float a0 = 0.f, a1 = 0.f, a2 = 0.f, a3 = 0.f;
#pragma unroll
        for (int d = 0; d < ND; ++d) {
            h2 wm = __builtin_bit_cast(h2, w[d]);
            a0 = __builtin_amdgcn_fdot2(__builtin_bit_cast(h2, K2[0][d]), wm, a0, false);
            a1 = __builtin_amdgcn_fdot2(__builtin_bit_cast(h2, K2[1][d]), wm, a1, false);
            a2 = __builtin_amdgcn_fdot2(__builtin_bit_cast(h2, K2[2][d]), wm, a2, false);
            a3 = __builtin_amdgcn_fdot2(__builtin_bit_cast(h2, K2[3][d]), wm, a3, false);
        }
        unsigned nx0 = __builtin_bit_cast(unsigned,
            pack2(__builtin_amdgcn_rcpf(a0), __builtin_amdgcn_rcpf(a1)));
        unsigned nx1 = __builtin_bit_cast(unsigned,
            pack2(__builtin_amdgcn_rcpf(a2), __builtin_amdgcn_rcpf(a3)));
        unsigned ns1a = shr1(nx0), ns1b = shr1(nx1);
        unsigned nl1a = shl1(nx0), nl1b = shl1(nx1);
        unsigned nw13 = shl1(nl1a);

        // half 2: rows 4..7 (overlaps half-1 funnel)
        float a4 = 0.f, a5 = 0.f, a6 = 0.f, a7 = 0.f;
#pragma unroll
        for (int d = 0; d < ND; ++d) {
            h2 wm = __builtin_bit_cast(h2, w[d]);
            a4 = __builtin_amdgcn_fdot2(__builtin_bit_cast(h2, K2[4][d]), wm, a4, false);
            a5 = __builtin_amdgcn_fdot2(__builtin_bit_cast(h2, K2[5][d]), wm, a5, false);
            a6 = __builtin_amdgcn_fdot2(__builtin_bit_cast(h2, K2[6][d]), wm, a6, false);
            a7 = __builtin_amdgcn_fdot2(__builtin_bit_cast(h2, K2[7][d]), wm, a7, false);
        }
        unsigned nx2 = __builtin_bit_cast(unsigned,
            pack2(__builtin_amdgcn_rcpf(a4), __builtin_amdgcn_rcpf(a5)));
        unsigned nx3 = __builtin_bit_cast(unsigned,
            pack2(__builtin_amdgcn_rcpf(a6), __builtin_amdgcn_rcpf(a7)));
        unsigned ns1c = shr1(nx2), ns1d = shr1(nx3);
        unsigned nl1c = shl1(nx2), nl1d = shl1(nx3);

        x0 = nx0; x1 = nx1; x2 = nx2; x3 = nx3;
        w[0] = shr1(ns1d);
        w[1] = ns1a;  w[2] = ns1b;  w[3] = ns1c;  w[4] = ns1d;
        w[5] = nx0;   w[6] = nx1;   w[7] = nx2;   w[8] = nx3;
        w[9] = nl1a;  w[10] = nl1b; w[11] = nl1c; w[12] = nl1d;
        w[13] = nw13;
    }
    // peeled app 200: update x only; w stays = window of app-199 state (c)
    {
        float a[8] = {0.f, 0.f, 0.f, 0.f, 0.f, 0.f, 0.f, 0.f};
#pragma unroll
        for (int d = 0; d < ND; ++d) {
            h2 wm = __builtin_bit_cast(h2, w[d]);
#pragma unroll
            for (int r = 0; r < 8; ++r)
                a[r] = __builtin_amdgcn_fdot2(__builtin_bit_cast(h2, K2[r][d]), wm, a[r], false);
        }
        x0 = __builtin_bit_cast(unsigned,
            pack2(__builtin_amdgcn_rcpf(a[0]), __builtin_amdgcn_rcpf(a[1])));
        x1 = __builtin_bit_cast(unsigned,
            pack2(__builtin_amdgcn_rcpf(a[2]), __builtin_amdgcn_rcpf(a[3])));
        x2 = __builtin_bit_cast(unsigned,
            pack2(__builtin_amdgcn_rcpf(a[4]), __builtin_amdgcn_rcpf(a[5])));
        x3 = __builtin_bit_cast(unsigned,
            pack2(__builtin_amdgcn_rcpf(a[6]), __builtin_amdgcn_rcpf(a[7])));
    }

    // ---- epilogue: out_row = r_a * sum_{gc<K} K[a][gc] c_gc ----
    float accK[8] = {0.f, 0.f, 0.f, 0.f, 0.f, 0.f, 0.f, 0.f};
#pragma unroll
    for (int d = 0; d < ND; ++d) {
        int g0 = gb + 2 * d, g1 = g0 + 1;
        h2 cw = __builtin_bit_cast(h2, w[d]);
        float c0 = (g0 >= 0 && g0 < KTOP) ? (float)cw[0] : 0.f;
        float c1 = (g1 >= 0 && g1 < KTOP) ? (float)cw[1] : 0.f;
        h2 cm = pack2(c0, c1);
#pragma unroll
        for (int r = 0; r < 8; ++r)
            accK[r] = __builtin_amdgcn_fdot2(__builtin_bit_cast(h2, K2[r][d]), cm, accK[r], false);
    }
    unsigned xs[4] = {x0, x1, x2, x3};
#pragma unroll
    for (int k = 0; k < 4; ++k) {
        h2 xr = __builtin_bit_cast(h2, xs[k]);
        out[b * N + ti[r0 + 2 * k]]     = (float)xr[0] * accK[2 * k];
        out[b * N + ti[r0 + 2 * k + 1]] = (float)xr[1] * accK[2 * k + 1];
    }
}

extern "C" void kernel_launch(void* const* d_in, const int* in_sizes, int n_in,
                              void* d_out, int out_size, void* d_ws, size_t ws_size,
                              hipStream_t stream) {
    const float* scores = (const float*)d_in[0];
    float* out = (float*)d_out;
    sinkhorn_topk_kernel<<<dim3(BATCH), dim3(64), 0, stream>>>(scores, out);
}

// Round 14
// 131.574 us; speedup vs baseline: 1.0059x; 1.0059x over previous
//
#include <hip/hip_runtime.h>

// Sinkhorn top-k, sorted-value domain, x <- 1/(Mx), 200 apps.
// R14 = R12 (radius 10, split-half funnel overlap, waves_per_eu(1,1))
//     + #pragma unroll 2 on the app loop: scheduler sees app t and t+1 in
//       one block and can issue t+1's half-1 dots under t's half-2 funnel
//       (rcp/DPP latency) -- the last exposed serial segment (~255 stall
//       cyc/app measured). Pin dropped (R13 proved it a no-op).

#define N      512
#define BATCH  16
#define KTOP   50
#define NAPPS  200
#define ND     14          // window dwords: global dwords 4l-5 .. 4l+8
#define COEF   1442.6950408889634f   // log2(e)/EPSILON, EPSILON=1e-3
#define ONEH2  0x3C003C00u

typedef _Float16 h2 __attribute__((ext_vector_type(2)));

static __device__ __forceinline__ h2 pack2(float a, float b) {
    return __builtin_bit_cast(h2, __builtin_amdgcn_cvt_pkrtz(a, b));
}
static __device__ __forceinline__ unsigned shr1(unsigned v) {   // lane i <- i-1, 0-fill
    return (unsigned)__builtin_amdgcn_update_dpp(0, (int)v, 0x138, 0xF, 0xF, true);
}
static __device__ __forceinline__ unsigned shl1(unsigned v) {   // lane i <- i+1, 0-fill
    return (unsigned)__builtin_amdgcn_update_dpp(0, (int)v, 0x130, 0xF, 0xF, true);
}

__global__
__attribute__((amdgpu_flat_work_group_size(64, 64), amdgpu_waves_per_eu(1, 1)))
void sinkhorn_topk_kernel(const float* __restrict__ scores,
                          float* __restrict__ out) {
    __shared__ __align__(16) float tv[N];
    __shared__ int                 ti[N];

    const int lane = threadIdx.x;           // 0..63
    const int b    = blockIdx.x;

    ((float4*)tv)[2 * lane]     = ((const float4*)(scores + b * N))[2 * lane];
    ((float4*)tv)[2 * lane + 1] = ((const float4*)(scores + b * N))[2 * lane + 1];
#pragma unroll
    for (int r = 0; r < 8; ++r) ti[8 * lane + r] = 8 * lane + r;
    __syncthreads();

    // ---- bitonic sort, descending ----
    for (int k = 2; k <= N; k <<= 1) {
        for (int j = k >> 1; j > 0; j >>= 1) {
#pragma unroll
            for (int e = 0; e < 4; ++e) {
                int q = lane + e * 64;
                int i = ((q & ~(j - 1)) << 1) | (q & (j - 1));
                int p = i | j;
                float va = tv[i], vb = tv[p];
                bool up = ((i & k) == 0);
                bool sw = up ? (va < vb) : (va > vb);
                if (sw) {
                    tv[i] = vb; tv[p] = va;
                    int t_ = ti[i]; ti[i] = ti[p]; ti[p] = t_;
                }
            }
            __syncthreads();
        }
    }

    // ---- K band: rows 8l..8l+7, col halves 8l-10..8l+17 (14 dwords) ----
    const int r0 = 8 * lane;
    const int gb = r0 - 10;
    float trow[8];
#pragma unroll
    for (int r = 0; r < 8; ++r) trow[r] = tv[r0 + r];

    h2 K2[8][ND];                           // 112 dwords/lane
#pragma unroll
    for (int d = 0; d < ND; ++d) {
        int g0 = gb + 2 * d, g1 = g0 + 1;
        int c0 = min(max(g0, 0), N - 1), c1 = min(max(g1, 0), N - 1);
        float s0 = tv[c0], s1 = tv[c1];
#pragma unroll
        for (int r = 0; r < 8; ++r) {
            float d0 = trow[r] - s0, d1 = trow[r] - s1;
            K2[r][d] = pack2(exp2f(-COEF * d0 * d0), exp2f(-COEF * d1 * d1));
        }
    }

    // ---- x (app 0) and its window ----
    unsigned x0 = ONEH2, x1 = ONEH2, x2 = ONEH2, x3 = ONEH2;
    unsigned w[ND];
    {
        unsigned s1a = shr1(x0), s1b = shr1(x1), s1c = shr1(x2), s1d = shr1(x3);
        unsigned l1a = shl1(x0), l1b = shl1(x1), l1c = shl1(x2), l1d = shl1(x3);
        w[0] = shr1(s1d);
        w[1] = s1a;  w[2] = s1b;  w[3] = s1c;  w[4] = s1d;
        w[5] = x0;   w[6] = x1;   w[7] = x2;   w[8] = x3;
        w[9] = l1a;  w[10] = l1b; w[11] = l1c; w[12] = l1d;
        w[13] = shl1(l1a);
    }

    // ---- 199 full apps (dots + rebuild), then 1 peeled app ----
#pragma unroll 2
    for (int t = 0; t < NAPPS - 1; ++t) {
        // half 1: rows 0..3
        float a0 = 0.f, a1 = 0.f, a2 = 0.f, a3 = 0.f;
#pragma unroll
        for (int d = 0; d < ND; ++d) {
            h2 wm = __builtin_bit_cast(h2, w[d]);
            a0 = __builtin_amdgcn_fdot2(K2[0][d], wm, a0, false);
            a1 = __builtin_amdgcn_fdot2(K2[1][d], wm, a1, false);
            a2 = __builtin_amdgcn_fdot2(K2[2][d], wm, a2, false);
            a3 = __builtin_amdgcn_fdot2(K2[3][d], wm, a3, false);
        }
        unsigned nx0 = __builtin_bit_cast(unsigned,
            pack2(__builtin_amdgcn_rcpf(a0), __builtin_amdgcn_rcpf(a1)));
        unsigned nx1 = __builtin_bit_cast(unsigned,
            pack2(__builtin_amdgcn_rcpf(a2), __builtin_amdgcn_rcpf(a3)));
        unsigned ns1a = shr1(nx0), ns1b = shr1(nx1);
        unsigned nl1a = shl1(nx0), nl1b = shl1(nx1);
        unsigned nw13 = shl1(nl1a);

        // half 2: rows 4..7 (overlaps half-1 funnel)
        float a4 = 0.f, a5 = 0.f, a6 = 0.f, a7 = 0.f;
#pragma unroll
        for (int d = 0; d < ND; ++d) {
            h2 wm = __builtin_bit_cast(h2, w[d]);
            a4 = __builtin_amdgcn_fdot2(K2[4][d], wm, a4, false);
            a5 = __builtin_amdgcn_fdot2(K2[5][d], wm, a5, false);
            a6 = __builtin_amdgcn_fdot2(K2[6][d], wm, a6, false);
            a7 = __builtin_amdgcn_fdot2(K2[7][d], wm, a7, false);
        }
        unsigned nx2 = __builtin_bit_cast(unsigned,
            pack2(__builtin_amdgcn_rcpf(a4), __builtin_amdgcn_rcpf(a5)));
        unsigned nx3 = __builtin_bit_cast(unsigned,
            pack2(__builtin_amdgcn_rcpf(a6), __builtin_amdgcn_rcpf(a7)));
        unsigned ns1c = shr1(nx2), ns1d = shr1(nx3);
        unsigned nl1c = shl1(nx2), nl1d = shl1(nx3);

        x0 = nx0; x1 = nx1; x2 = nx2; x3 = nx3;
        w[0] = shr1(ns1d);
        w[1] = ns1a;  w[2] = ns1b;  w[3] = ns1c;  w[4] = ns1d;
        w[5] = nx0;   w[6] = nx1;   w[7] = nx2;   w[8] = nx3;
        w[9] = nl1a;  w[10] = nl1b; w[11] = nl1c; w[12] = nl1d;
        w[13] = nw13;
    }
    // peeled app 200: update x only; w stays = window of app-199 state (c)
    {
        float a[8] = {0.f, 0.f, 0.f, 0.f, 0.f, 0.f, 0.f, 0.f};
#pragma unroll
        for (int d = 0; d < ND; ++d) {
            h2 wm = __builtin_bit_cast(h2, w[d]);
#pragma unroll
            for (int r = 0; r < 8; ++r)
                a[r] = __builtin_amdgcn_fdot2(K2[r][d], wm, a[r], false);
        }
        x0 = __builtin_bit_cast(unsigned,
            pack2(__builtin_amdgcn_rcpf(a[0]), __builtin_amdgcn_rcpf(a[1])));
        x1 = __builtin_bit_cast(unsigned,
            pack2(__builtin_amdgcn_rcpf(a[2]), __builtin_amdgcn_rcpf(a[3])));
        x2 = __builtin_bit_cast(unsigned,
            pack2(__builtin_amdgcn_rcpf(a[4]), __builtin_amdgcn_rcpf(a[5])));
        x3 = __builtin_bit_cast(unsigned,
            pack2(__builtin_amdgcn_rcpf(a[6]), __builtin_amdgcn_rcpf(a[7])));
    }

    // ---- epilogue: out_row = r_a * sum_{gc<K} K[a][gc] c_gc ----
    float accK[8] = {0.f, 0.f, 0.f, 0.f, 0.f, 0.f, 0.f, 0.f};
#pragma unroll
    for (int d = 0; d < ND; ++d) {
        int g0 = gb + 2 * d, g1 = g0 + 1;
        h2 cw = __builtin_bit_cast(h2, w[d]);
        float c0 = (g0 >= 0 && g0 < KTOP) ? (float)cw[0] : 0.f;
        float c1 = (g1 >= 0 && g1 < KTOP) ? (float)cw[1] : 0.f;
        h2 cm = pack2(c0, c1);
#pragma unroll
        for (int r = 0; r < 8; ++r)
            accK[r] = __builtin_amdgcn_fdot2(K2[r][d], cm, accK[r], false);
    }
    unsigned xs[4] = {x0, x1, x2, x3};
#pragma unroll
    for (int k = 0; k < 4; ++k) {
        h2 xr = __builtin_bit_cast(h2, xs[k]);
        out[b * N + ti[r0 + 2 * k]]     = (float)xr[0] * accK[2 * k];
        out[b * N + ti[r0 + 2 * k + 1]] = (float)xr[1] * accK[2 * k + 1];
    }
}

extern "C" void kernel_launch(void* const* d_in, const int* in_sizes, int n_in,
                              void* d_out, int out_size, void* d_ws, size_t ws_size,
                              hipStream_t stream) {
    const float* scores = (const float*)d_in[0];
    float* out = (float*)d_out;
    sinkhorn_topk_kernel<<<dim3(BATCH), dim3(64), 0, stream>>>(scores, out);
}

// Round 15
// 130.204 us; speedup vs baseline: 1.0165x; 1.0105x over previous
//
#include <hip/hip_runtime.h>

// Sinkhorn top-k, sorted-value domain, x <- 1/(Mx), 200 apps.
// R15 = R12 with hybrid chain interleave: d=0..9 runs all 8 acc chains
// interleaved (16-cyc dependent-reuse distance kills VOP3P dot dep-stall);
// only the d=10..13 tails (16 dots each) run 4-way so rows 0-3 release
// early into funnel-1, which overlaps rows 4-7's tail. acc zero-init folded
// into the d=0 dot. Arithmetic bit-identical to R12.

#define N      512
#define BATCH  16
#define KTOP   50
#define NAPPS  200
#define ND     14          // window dwords: global dwords 4l-5 .. 4l+8
#define COEF   1442.6950408889634f   // log2(e)/EPSILON, EPSILON=1e-3
#define ONEH2  0x3C003C00u

typedef _Float16 h2 __attribute__((ext_vector_type(2)));

static __device__ __forceinline__ h2 pack2(float a, float b) {
    return __builtin_bit_cast(h2, __builtin_amdgcn_cvt_pkrtz(a, b));
}
static __device__ __forceinline__ unsigned shr1(unsigned v) {   // lane i <- i-1, 0-fill
    return (unsigned)__builtin_amdgcn_update_dpp(0, (int)v, 0x138, 0xF, 0xF, true);
}
static __device__ __forceinline__ unsigned shl1(unsigned v) {   // lane i <- i+1, 0-fill
    return (unsigned)__builtin_amdgcn_update_dpp(0, (int)v, 0x130, 0xF, 0xF, true);
}

__global__
__attribute__((amdgpu_flat_work_group_size(64, 64), amdgpu_waves_per_eu(1, 1)))
void sinkhorn_topk_kernel(const float* __restrict__ scores,
                          float* __restrict__ out) {
    __shared__ __align__(16) float tv[N];
    __shared__ int                 ti[N];

    const int lane = threadIdx.x;           // 0..63
    const int b    = blockIdx.x;

    ((float4*)tv)[2 * lane]     = ((const float4*)(scores + b * N))[2 * lane];
    ((float4*)tv)[2 * lane + 1] = ((const float4*)(scores + b * N))[2 * lane + 1];
#pragma unroll
    for (int r = 0; r < 8; ++r) ti[8 * lane + r] = 8 * lane + r;
    __syncthreads();

    // ---- bitonic sort, descending ----
    for (int k = 2; k <= N; k <<= 1) {
        for (int j = k >> 1; j > 0; j >>= 1) {
#pragma unroll
            for (int e = 0; e < 4; ++e) {
                int q = lane + e * 64;
                int i = ((q & ~(j - 1)) << 1) | (q & (j - 1));
                int p = i | j;
                float va = tv[i], vb = tv[p];
                bool up = ((i & k) == 0);
                bool sw = up ? (va < vb) : (va > vb);
                if (sw) {
                    tv[i] = vb; tv[p] = va;
                    int t_ = ti[i]; ti[i] = ti[p]; ti[p] = t_;
                }
            }
            __syncthreads();
        }
    }

    // ---- K band: rows 8l..8l+7, col halves 8l-10..8l+17 (14 dwords) ----
    const int r0 = 8 * lane;
    const int gb = r0 - 10;
    float trow[8];
#pragma unroll
    for (int r = 0; r < 8; ++r) trow[r] = tv[r0 + r];

    h2 K2[8][ND];                           // 112 dwords/lane
#pragma unroll
    for (int d = 0; d < ND; ++d) {
        int g0 = gb + 2 * d, g1 = g0 + 1;
        int c0 = min(max(g0, 0), N - 1), c1 = min(max(g1, 0), N - 1);
        float s0 = tv[c0], s1 = tv[c1];
#pragma unroll
        for (int r = 0; r < 8; ++r) {
            float d0 = trow[r] - s0, d1 = trow[r] - s1;
            K2[r][d] = pack2(exp2f(-COEF * d0 * d0), exp2f(-COEF * d1 * d1));
        }
    }

    // ---- x (app 0) and its window ----
    unsigned x0 = ONEH2, x1 = ONEH2, x2 = ONEH2, x3 = ONEH2;
    unsigned w[ND];
    {
        unsigned s1a = shr1(x0), s1b = shr1(x1), s1c = shr1(x2), s1d = shr1(x3);
        unsigned l1a = shl1(x0), l1b = shl1(x1), l1c = shl1(x2), l1d = shl1(x3);
        w[0] = shr1(s1d);
        w[1] = s1a;  w[2] = s1b;  w[3] = s1c;  w[4] = s1d;
        w[5] = x0;   w[6] = x1;   w[7] = x2;   w[8] = x3;
        w[9] = l1a;  w[10] = l1b; w[11] = l1c; w[12] = l1d;
        w[13] = shl1(l1a);
    }

    // ---- 199 full apps, then 1 peeled app ----
    for (int t = 0; t < NAPPS - 1; ++t) {
        // body d=0..9: ALL 8 chains interleaved (no dep stall); acc init folded
        h2 wm0 = __builtin_bit_cast(h2, w[0]);
        float a0 = __builtin_amdgcn_fdot2(K2[0][0], wm0, 0.0f, false);
        float a1 = __builtin_amdgcn_fdot2(K2[1][0], wm0, 0.0f, false);
        float a2 = __builtin_amdgcn_fdot2(K2[2][0], wm0, 0.0f, false);
        float a3 = __builtin_amdgcn_fdot2(K2[3][0], wm0, 0.0f, false);
        float a4 = __builtin_amdgcn_fdot2(K2[4][0], wm0, 0.0f, false);
        float a5 = __builtin_amdgcn_fdot2(K2[5][0], wm0, 0.0f, false);
        float a6 = __builtin_amdgcn_fdot2(K2[6][0], wm0, 0.0f, false);
        float a7 = __builtin_amdgcn_fdot2(K2[7][0], wm0, 0.0f, false);
#pragma unroll
        for (int d = 1; d < 10; ++d) {
            h2 wm = __builtin_bit_cast(h2, w[d]);
            a0 = __builtin_amdgcn_fdot2(K2[0][d], wm, a0, false);
            a1 = __builtin_amdgcn_fdot2(K2[1][d], wm, a1, false);
            a2 = __builtin_amdgcn_fdot2(K2[2][d], wm, a2, false);
            a3 = __builtin_amdgcn_fdot2(K2[3][d], wm, a3, false);
            a4 = __builtin_amdgcn_fdot2(K2[4][d], wm, a4, false);
            a5 = __builtin_amdgcn_fdot2(K2[5][d], wm, a5, false);
            a6 = __builtin_amdgcn_fdot2(K2[6][d], wm, a6, false);
            a7 = __builtin_amdgcn_fdot2(K2[7][d], wm, a7, false);
        }
        // tail rows 0..3 (16 dots, 4-way)
#pragma unroll
        for (int d = 10; d < ND; ++d) {
            h2 wm = __builtin_bit_cast(h2, w[d]);
            a0 = __builtin_amdgcn_fdot2(K2[0][d], wm, a0, false);
            a1 = __builtin_amdgcn_fdot2(K2[1][d], wm, a1, false);
            a2 = __builtin_amdgcn_fdot2(K2[2][d], wm, a2, false);
            a3 = __builtin_amdgcn_fdot2(K2[3][d], wm, a3, false);
        }
        // funnel 1 (overlaps rows 4..7 tail below)
        unsigned nx0 = __builtin_bit_cast(unsigned,
            pack2(__builtin_amdgcn_rcpf(a0), __builtin_amdgcn_rcpf(a1)));
        unsigned nx1 = __builtin_bit_cast(unsigned,
            pack2(__builtin_amdgcn_rcpf(a2), __builtin_amdgcn_rcpf(a3)));
        unsigned ns1a = shr1(nx0), ns1b = shr1(nx1);
        unsigned nl1a = shl1(nx0), nl1b = shl1(nx1);
        unsigned nw13 = shl1(nl1a);

        // tail rows 4..7 (16 dots, 4-way)
#pragma unroll
        for (int d = 10; d < ND; ++d) {
            h2 wm = __builtin_bit_cast(h2, w[d]);
            a4 = __builtin_amdgcn_fdot2(K2[4][d], wm, a4, false);
            a5 = __builtin_amdgcn_fdot2(K2[5][d], wm, a5, false);
            a6 = __builtin_amdgcn_fdot2(K2[6][d], wm, a6, false);
            a7 = __builtin_amdgcn_fdot2(K2[7][d], wm, a7, false);
        }
        // funnel 2 + window rebuild
        unsigned nx2 = __builtin_bit_cast(unsigned,
            pack2(__builtin_amdgcn_rcpf(a4), __builtin_amdgcn_rcpf(a5)));
        unsigned nx3 = __builtin_bit_cast(unsigned,
            pack2(__builtin_amdgcn_rcpf(a6), __builtin_amdgcn_rcpf(a7)));
        unsigned ns1c = shr1(nx2), ns1d = shr1(nx3);
        unsigned nl1c = shl1(nx2), nl1d = shl1(nx3);

        x0 = nx0; x1 = nx1; x2 = nx2; x3 = nx3;
        w[0] = shr1(ns1d);
        w[1] = ns1a;  w[2] = ns1b;  w[3] = ns1c;  w[4] = ns1d;
        w[5] = nx0;   w[6] = nx1;   w[7] = nx2;   w[8] = nx3;
        w[9] = nl1a;  w[10] = nl1b; w[11] = nl1c; w[12] = nl1d;
        w[13] = nw13;
    }
    // peeled app 200: update x only; w stays = window of app-199 state (c)
    {
        float a[8] = {0.f, 0.f, 0.f, 0.f, 0.f, 0.f, 0.f, 0.f};
#pragma unroll
        for (int d = 0; d < ND; ++d) {
            h2 wm = __builtin_bit_cast(h2, w[d]);
#pragma unroll
            for (int r = 0; r < 8; ++r)
                a[r] = __builtin_amdgcn_fdot2(K2[r][d], wm, a[r], false);
        }
        x0 = __builtin_bit_cast(unsigned,
            pack2(__builtin_amdgcn_rcpf(a[0]), __builtin_amdgcn_rcpf(a[1])));
        x1 = __builtin_bit_cast(unsigned,
            pack2(__builtin_amdgcn_rcpf(a[2]), __builtin_amdgcn_rcpf(a[3])));
        x2 = __builtin_bit_cast(unsigned,
            pack2(__builtin_amdgcn_rcpf(a[4]), __builtin_amdgcn_rcpf(a[5])));
        x3 = __builtin_bit_cast(unsigned,
            pack2(__builtin_amdgcn_rcpf(a[6]), __builtin_amdgcn_rcpf(a[7])));
    }

    // ---- epilogue: out_row = r_a * sum_{gc<K} K[a][gc] c_gc ----
    float accK[8] = {0.f, 0.f, 0.f, 0.f, 0.f, 0.f, 0.f, 0.f};
#pragma unroll
    for (int d = 0; d < ND; ++d) {
        int g0 = gb + 2 * d, g1 = g0 + 1;
        h2 cw = __builtin_bit_cast(h2, w[d]);
        float c0 = (g0 >= 0 && g0 < KTOP) ? (float)cw[0] : 0.f;
        float c1 = (g1 >= 0 && g1 < KTOP) ? (float)cw[1] : 0.f;
        h2 cm = pack2(c0, c1);
#pragma unroll
        for (int r = 0; r < 8; ++r)
            accK[r] = __builtin_amdgcn_fdot2(K2[r][d], cm, accK[r], false);
    }
    unsigned xs[4] = {x0, x1, x2, x3};
#pragma unroll
    for (int k = 0; k < 4; ++k) {
        h2 xr = __builtin_bit_cast(h2, xs[k]);
        out[b * N + ti[r0 + 2 * k]]     = (float)xr[0] * accK[2 * k];
        out[b * N + ti[r0 + 2 * k + 1]] = (float)xr[1] * accK[2 * k + 1];
    }
}

extern "C" void kernel_launch(void* const* d_in, const int* in_sizes, int n_in,
                              void* d_out, int out_size, void* d_ws, size_t ws_size,
                              hipStream_t stream) {
    const float* scores = (const float*)d_in[0];
    float* out = (float*)d_out;
    sinkhorn_topk_kernel<<<dim3(BATCH), dim3(64), 0, stream>>>(scores, out);
}

// Round 16
// 122.069 us; speedup vs baseline: 1.0842x; 1.0666x over previous
//
#include <hip/hip_runtime.h>

// Sinkhorn top-k, sorted-value domain, x <- 1/(Mx), 200 apps.
// R16 = R15 with exact per-row windows: row r only needs radius 10 = 11
// dwords starting at dword (r>>1) of the 14-dword shared window (row pairs
// share a span). Dots/app 112 -> 88; K2 112 -> 88 dwords. Min radius still
// 10, so the (4-for-4) edge^2 law predicts absmax ~8.6e-3 unchanged.

#define N      512
#define BATCH  16
#define KTOP   50
#define NAPPS  200
#define ND     14          // window dwords: global dwords 4l-5 .. 4l+8
#define NJ     11          // dots per row
#define COEF   1442.6950408889634f   // log2(e)/EPSILON, EPSILON=1e-3
#define ONEH2  0x3C003C00u

typedef _Float16 h2 __attribute__((ext_vector_type(2)));

static __device__ __forceinline__ h2 pack2(float a, float b) {
    return __builtin_bit_cast(h2, __builtin_amdgcn_cvt_pkrtz(a, b));
}
static __device__ __forceinline__ unsigned shr1(unsigned v) {   // lane i <- i-1, 0-fill
    return (unsigned)__builtin_amdgcn_update_dpp(0, (int)v, 0x138, 0xF, 0xF, true);
}
static __device__ __forceinline__ unsigned shl1(unsigned v) {   // lane i <- i+1, 0-fill
    return (unsigned)__builtin_amdgcn_update_dpp(0, (int)v, 0x130, 0xF, 0xF, true);
}

__global__
__attribute__((amdgpu_flat_work_group_size(64, 64), amdgpu_waves_per_eu(1, 1)))
void sinkhorn_topk_kernel(const float* __restrict__ scores,
                          float* __restrict__ out) {
    __shared__ __align__(16) float tv[N];
    __shared__ int                 ti[N];

    const int lane = threadIdx.x;           // 0..63
    const int b    = blockIdx.x;

    ((float4*)tv)[2 * lane]     = ((const float4*)(scores + b * N))[2 * lane];
    ((float4*)tv)[2 * lane + 1] = ((const float4*)(scores + b * N))[2 * lane + 1];
#pragma unroll
    for (int r = 0; r < 8; ++r) ti[8 * lane + r] = 8 * lane + r;
    __syncthreads();

    // ---- bitonic sort, descending ----
    for (int k = 2; k <= N; k <<= 1) {
        for (int j = k >> 1; j > 0; j >>= 1) {
#pragma unroll
            for (int e = 0; e < 4; ++e) {
                int q = lane + e * 64;
                int i = ((q & ~(j - 1)) << 1) | (q & (j - 1));
                int p = i | j;
                float va = tv[i], vb = tv[p];
                bool up = ((i & k) == 0);
                bool sw = up ? (va < vb) : (va > vb);
                if (sw) {
                    tv[i] = vb; tv[p] = va;
                    int t_ = ti[i]; ti[i] = ti[p]; ti[p] = t_;
                }
            }
            __syncthreads();
        }
    }

    // ---- K band: row r uses window dwords (r>>1)..(r>>1)+10 ----
    const int r0 = 8 * lane;
    const int gb = r0 - 10;                 // half-index of window dword 0
    float trow[8];
#pragma unroll
    for (int r = 0; r < 8; ++r) trow[r] = tv[r0 + r];

    h2 K2[8][NJ];                           // 88 dwords/lane
#pragma unroll
    for (int j = 0; j < NJ; ++j) {
#pragma unroll
        for (int r = 0; r < 8; ++r) {
            int d  = (r >> 1) + j;          // window dword slot
            int g0 = gb + 2 * d, g1 = g0 + 1;
            int c0 = min(max(g0, 0), N - 1), c1 = min(max(g1, 0), N - 1);
            float s0 = tv[c0], s1 = tv[c1];
            float d0 = trow[r] - s0, d1 = trow[r] - s1;
            K2[r][j] = pack2(exp2f(-COEF * d0 * d0), exp2f(-COEF * d1 * d1));
        }
    }

    // ---- x (app 0) and its window ----
    unsigned x0 = ONEH2, x1 = ONEH2, x2 = ONEH2, x3 = ONEH2;
    unsigned w[ND];
    {
        unsigned s1a = shr1(x0), s1b = shr1(x1), s1c = shr1(x2), s1d = shr1(x3);
        unsigned l1a = shl1(x0), l1b = shl1(x1), l1c = shl1(x2), l1d = shl1(x3);
        w[0] = shr1(s1d);
        w[1] = s1a;  w[2] = s1b;  w[3] = s1c;  w[4] = s1d;
        w[5] = x0;   w[6] = x1;   w[7] = x2;   w[8] = x3;
        w[9] = l1a;  w[10] = l1b; w[11] = l1c; w[12] = l1d;
        w[13] = shl1(l1a);
    }

    // ---- 199 full apps, then 1 peeled app ----
    for (int t = 0; t < NAPPS - 1; ++t) {
        // j=0, acc init folded into the dot (8-way interleave throughout body)
        float a0 = __builtin_amdgcn_fdot2(K2[0][0], __builtin_bit_cast(h2, w[0]), 0.0f, false);
        float a1 = __builtin_amdgcn_fdot2(K2[1][0], __builtin_bit_cast(h2, w[0]), 0.0f, false);
        float a2 = __builtin_amdgcn_fdot2(K2[2][0], __builtin_bit_cast(h2, w[1]), 0.0f, false);
        float a3 = __builtin_amdgcn_fdot2(K2[3][0], __builtin_bit_cast(h2, w[1]), 0.0f, false);
        float a4 = __builtin_amdgcn_fdot2(K2[4][0], __builtin_bit_cast(h2, w[2]), 0.0f, false);
        float a5 = __builtin_amdgcn_fdot2(K2[5][0], __builtin_bit_cast(h2, w[2]), 0.0f, false);
        float a6 = __builtin_amdgcn_fdot2(K2[6][0], __builtin_bit_cast(h2, w[3]), 0.0f, false);
        float a7 = __builtin_amdgcn_fdot2(K2[7][0], __builtin_bit_cast(h2, w[3]), 0.0f, false);
#pragma unroll
        for (int j = 1; j < 8; ++j) {
            h2 wA = __builtin_bit_cast(h2, w[j]);
            h2 wB = __builtin_bit_cast(h2, w[j + 1]);
            h2 wC = __builtin_bit_cast(h2, w[j + 2]);
            h2 wD = __builtin_bit_cast(h2, w[j + 3]);
            a0 = __builtin_amdgcn_fdot2(K2[0][j], wA, a0, false);
            a1 = __builtin_amdgcn_fdot2(K2[1][j], wA, a1, false);
            a2 = __builtin_amdgcn_fdot2(K2[2][j], wB, a2, false);
            a3 = __builtin_amdgcn_fdot2(K2[3][j], wB, a3, false);
            a4 = __builtin_amdgcn_fdot2(K2[4][j], wC, a4, false);
            a5 = __builtin_amdgcn_fdot2(K2[5][j], wC, a5, false);
            a6 = __builtin_amdgcn_fdot2(K2[6][j], wD, a6, false);
            a7 = __builtin_amdgcn_fdot2(K2[7][j], wD, a7, false);
        }
        // tail rows 0..3 (j=8..10)
#pragma unroll
        for (int j = 8; j < NJ; ++j) {
            h2 wA = __builtin_bit_cast(h2, w[j]);
            h2 wB = __builtin_bit_cast(h2, w[j + 1]);
            a0 = __builtin_amdgcn_fdot2(K2[0][j], wA, a0, false);
            a1 = __builtin_amdgcn_fdot2(K2[1][j], wA, a1, false);
            a2 = __builtin_amdgcn_fdot2(K2[2][j], wB, a2, false);
            a3 = __builtin_amdgcn_fdot2(K2[3][j], wB, a3, false);
        }
        // funnel 1 (overlaps rows 4..7 tail)
        unsigned nx0 = __builtin_bit_cast(unsigned,
            pack2(__builtin_amdgcn_rcpf(a0), __builtin_amdgcn_rcpf(a1)));
        unsigned nx1 = __builtin_bit_cast(unsigned,
            pack2(__builtin_amdgcn_rcpf(a2), __builtin_amdgcn_rcpf(a3)));
        unsigned ns1a = shr1(nx0), ns1b = shr1(nx1);
        unsigned nl1a = shl1(nx0), nl1b = shl1(nx1);
        unsigned nw13 = shl1(nl1a);

        // tail rows 4..7 (j=8..10)
#pragma unroll
        for (int j = 8; j < NJ; ++j) {
            h2 wC = __builtin_bit_cast(h2, w[j + 2]);
            h2 wD = __builtin_bit_cast(h2, w[j + 3]);
            a4 = __builtin_amdgcn_fdot2(K2[4][j], wC, a4, false);
            a5 = __builtin_amdgcn_fdot2(K2[5][j], wC, a5, false);
            a6 = __builtin_amdgcn_fdot2(K2[6][j], wD, a6, false);
            a7 = __builtin_amdgcn_fdot2(K2[7][j], wD, a7, false);
        }
        // funnel 2 + window rebuild
        unsigned nx2 = __builtin_bit_cast(unsigned,
            pack2(__builtin_amdgcn_rcpf(a4), __builtin_amdgcn_rcpf(a5)));
        unsigned nx3 = __builtin_bit_cast(unsigned,
            pack2(__builtin_amdgcn_rcpf(a6), __builtin_amdgcn_rcpf(a7)));
        unsigned ns1c = shr1(nx2), ns1d = shr1(nx3);
        unsigned nl1c = shl1(nx2), nl1d = shl1(nx3);

        x0 = nx0; x1 = nx1; x2 = nx2; x3 = nx3;
        w[0] = shr1(ns1d);
        w[1] = ns1a;  w[2] = ns1b;  w[3] = ns1c;  w[4] = ns1d;
        w[5] = nx0;   w[6] = nx1;   w[7] = nx2;   w[8] = nx3;
        w[9] = nl1a;  w[10] = nl1b; w[11] = nl1c; w[12] = nl1d;
        w[13] = nw13;
    }
    // peeled app 200: update x only; w stays = window of app-199 state (c)
    {
        float a[8] = {0.f, 0.f, 0.f, 0.f, 0.f, 0.f, 0.f, 0.f};
#pragma unroll
        for (int j = 0; j < NJ; ++j) {
#pragma unroll
            for (int r = 0; r < 8; ++r) {
                h2 wm = __builtin_bit_cast(h2, w[(r >> 1) + j]);
                a[r] = __builtin_amdgcn_fdot2(K2[r][j], wm, a[r], false);
            }
        }
        x0 = __builtin_bit_cast(unsigned,
            pack2(__builtin_amdgcn_rcpf(a[0]), __builtin_amdgcn_rcpf(a[1])));
        x1 = __builtin_bit_cast(unsigned,
            pack2(__builtin_amdgcn_rcpf(a[2]), __builtin_amdgcn_rcpf(a[3])));
        x2 = __builtin_bit_cast(unsigned,
            pack2(__builtin_amdgcn_rcpf(a[4]), __builtin_amdgcn_rcpf(a[5])));
        x3 = __builtin_bit_cast(unsigned,
            pack2(__builtin_amdgcn_rcpf(a[6]), __builtin_amdgcn_rcpf(a[7])));
    }

    // ---- epilogue: out_row = r_a * sum_{gc<K} K[a][gc] c_gc ----
    unsigned cmask[ND];
#pragma unroll
    for (int d = 0; d < ND; ++d) {
        int g0 = gb + 2 * d, g1 = g0 + 1;
        h2 cw = __builtin_bit_cast(h2, w[d]);
        float c0 = (g0 >= 0 && g0 < KTOP) ? (float)cw[0] : 0.f;
        float c1 = (g1 >= 0 && g1 < KTOP) ? (float)cw[1] : 0.f;
        cmask[d] = __builtin_bit_cast(unsigned, pack2(c0, c1));
    }
    float accK[8] = {0.f, 0.f, 0.f, 0.f, 0.f, 0.f, 0.f, 0.f};
#pragma unroll
    for (int j = 0; j < NJ; ++j) {
#pragma unroll
        for (int r = 0; r < 8; ++r) {
            h2 cm = __builtin_bit_cast(h2, cmask[(r >> 1) + j]);
            accK[r] = __builtin_amdgcn_fdot2(K2[r][j], cm, accK[r], false);
        }
    }
    unsigned xs[4] = {x0, x1, x2, x3};
#pragma unroll
    for (int k = 0; k < 4; ++k) {
        h2 xr = __builtin_bit_cast(h2, xs[k]);
        out[b * N + ti[r0 + 2 * k]]     = (float)xr[0] * accK[2 * k];
        out[b * N + ti[r0 + 2 * k + 1]] = (float)xr[1] * accK[2 * k + 1];
    }
}

extern "C" void kernel_launch(void* const* d_in, const int* in_sizes, int n_in,
                              void* d_out, int out_size, void* d_ws, size_t ws_size,
                              hipStream_t stream) {
    const float* scores = (const float*)d_in[0];
    float* out = (float*)d_out;
    sinkhorn_topk_kernel<<<dim3(BATCH), dim3(64), 0, stream>>>(scores, out);
}